// Round 5
// baseline (381.499 us; speedup 1.0000x reference)
//
#include <hip/hip_runtime.h>
#include <hip/hip_fp16.h>
#include <math.h>

#define T_LEN 1024
#define D_DIM 64
#define BATCH 32

// Skewed cost storage: element (r,c) lives at row (r + (c>>4)), col c.
// At DP step s, all 64 lanes read skewed row s contiguously (2 KB) -> coalesced.
#define SKEW_ROWS 1104                       // 1087 data diagonals + prefetch slack
#define SKEW_STRIDE ((size_t)SKEW_ROWS * T_LEN)   // halves per batch
#define PD 8                                 // prefetch depth (steps)

typedef __attribute__((ext_vector_type(2))) _Float16 h2v;

static __device__ __forceinline__ _Float16 hmin_(_Float16 a, _Float16 b) {
#if __has_builtin(__builtin_fminf16)
    return __builtin_fminf16(a, b);
#else
    return (b < a) ? b : a;
#endif
}
static __device__ __forceinline__ _Float16 hmax_(_Float16 a, _Float16 b) {
#if __has_builtin(__builtin_fmaxf16)
    return __builtin_fmaxf16(a, b);
#else
    return (a < b) ? b : a;
#endif
}
static __device__ __forceinline__ _Float16 med3h_(_Float16 a, _Float16 b, _Float16 c) {
    // call sites guarantee b >= a, so med3(a,b,c) == clamp(c,a,b)
#if __has_builtin(__builtin_amdgcn_fmed3h)
    return __builtin_amdgcn_fmed3h(a, b, c);
#else
    return hmax_(a, hmin_(b, c));
#endif
}

// ---------------------------------------------------------------------------
// INF staircase: skewed row s (s<63), cols >= 16*(s+1) must be half(+INF)
// (these are the "r<0" boundary cells for column blocks t>s). ~2 MB total.
// grid (63, 32) x 128 threads; one uint4 (8 halves) per thread.
// ---------------------------------------------------------------------------
__global__ __launch_bounds__(128) void fill_stairs_kernel(__half* __restrict__ ws) {
    int s = blockIdx.x;            // 0..62
    int b = blockIdx.y;            // 0..31
    int tid = threadIdx.x;         // 0..127
    int col0 = 16 * (s + 1);
    int n_u4 = (T_LEN - col0) >> 3;          // uint4 count
    if (tid < n_u4) {
        __half* row = ws + (size_t)b * SKEW_STRIDE + (size_t)s * T_LEN + col0;
        ((uint4*)row)[tid] = make_uint4(0x7C007C00u, 0x7C007C00u, 0x7C007C00u, 0x7C007C00u);
    }
}

// ---------------------------------------------------------------------------
// Pairwise distances, 128x128 tile, 256 threads, 8x8 micro-tile, BK=32 x2.
// Output fp16, written into the SKEWED layout: dest row = r + (col>>4).
// Within a thread's 8-col span the shift (col0>>4)+(TX>>1) is constant.
// ---------------------------------------------------------------------------
__global__ __launch_bounds__(256) void cost_kernel(const float* __restrict__ pred,
                                                   const float* __restrict__ targ,
                                                   __half* __restrict__ skew_base) {
    const int b = blockIdx.z;
    const float* P = pred + (size_t)b * T_LEN * D_DIM;
    const float* T = targ + (size_t)b * T_LEN * D_DIM;
    __half* C = skew_base + (size_t)b * SKEW_STRIDE;
    const int row0 = blockIdx.y * 128;
    const int col0 = blockIdx.x * 128;

    __shared__ __align__(16) float ps[32][132];  // ps[kk][r] = P[row0+r][k0+kk]
    __shared__ __align__(16) float ts[32][132];
    __shared__ float p2[128], t2[128];

    const int tid = threadIdx.x;

    {
        int r = tid & 127;
        const float* src = (tid < 128) ? (P + (size_t)(row0 + r) * D_DIM)
                                       : (T + (size_t)(col0 + r) * D_DIM);
        float s = 0.0f;
#pragma unroll
        for (int q = 0; q < 16; q++) {
            float4 v = ((const float4*)src)[q];
            s += v.x * v.x + v.y * v.y + v.z * v.z + v.w * v.w;
        }
        if (tid < 128) p2[r] = s; else t2[r] = s;
    }

    const int lane = tid & 63, wv = tid >> 6;
    const int TX = (lane & 7) + 8 * (wv & 1);    // 0..15
    const int TY = (lane >> 3) + 8 * (wv >> 1);  // 0..15

    float acc[8][8];
#pragma unroll
    for (int i = 0; i < 8; i++)
#pragma unroll
        for (int j = 0; j < 8; j++) acc[i][j] = 0.0f;

#pragma unroll
    for (int chunk = 0; chunk < 2; ++chunk) {
        __syncthreads();
#pragma unroll
        for (int it = 0; it < 4; ++it) {
            int idx = tid + 256 * it;            // 0..1023
            int row = idx >> 3;                  // 0..127
            int kc = idx & 7;                    // float4 chunk within 32-k
            float4 v = *(const float4*)(P + (size_t)(row0 + row) * D_DIM + 32 * chunk + 4 * kc);
            ps[4 * kc + 0][row] = v.x; ps[4 * kc + 1][row] = v.y;
            ps[4 * kc + 2][row] = v.z; ps[4 * kc + 3][row] = v.w;
            float4 w = *(const float4*)(T + (size_t)(col0 + row) * D_DIM + 32 * chunk + 4 * kc);
            ts[4 * kc + 0][row] = w.x; ts[4 * kc + 1][row] = w.y;
            ts[4 * kc + 2][row] = w.z; ts[4 * kc + 3][row] = w.w;
        }
        __syncthreads();

#pragma unroll
        for (int kk = 0; kk < 32; ++kk) {
            float4 a0 = *(const float4*)&ps[kk][8 * TY];
            float4 a1 = *(const float4*)&ps[kk][8 * TY + 4];
            float4 b0 = *(const float4*)&ts[kk][8 * TX];
            float4 b1 = *(const float4*)&ts[kk][8 * TX + 4];
            float av[8] = {a0.x, a0.y, a0.z, a0.w, a1.x, a1.y, a1.z, a1.w};
            float bv[8] = {b0.x, b0.y, b0.z, b0.w, b1.x, b1.y, b1.z, b1.w};
#pragma unroll
            for (int i = 0; i < 8; i++)
#pragma unroll
                for (int j = 0; j < 8; j++) acc[i][j] += av[i] * bv[j];
        }
    }
    __syncthreads();

    const int skew = (col0 >> 4) + (TX >> 1);    // constant per thread
#pragma unroll
    for (int i = 0; i < 8; i++) {
        float pa = p2[8 * TY + i];
        h2v o2[4];
#pragma unroll
        for (int j = 0; j < 4; j++) {
            float d0 = pa + t2[8 * TX + 2 * j]     - 2.0f * acc[i][2 * j];
            float d1 = pa + t2[8 * TX + 2 * j + 1] - 2.0f * acc[i][2 * j + 1];
            h2v h;
            h[0] = (_Float16)sqrtf(fmaxf(d0, 1e-12f));
            h[1] = (_Float16)sqrtf(fmaxf(d1, 1e-12f));
            o2[j] = h;
        }
        float4 st;
        st.x = __builtin_bit_cast(float, o2[0]);
        st.y = __builtin_bit_cast(float, o2[1]);
        st.z = __builtin_bit_cast(float, o2[2]);
        st.w = __builtin_bit_cast(float, o2[3]);
        __half* dst = C + (size_t)(row0 + 8 * TY + i + skew) * T_LEN + col0 + 8 * TX;
        *(float4*)dst = st;
    }
}

// ---------------------------------------------------------------------------
// Frechet DP, one wave per batch, fp16 math, skewed coalesced cost reads.
// SSA pipeline + sched_barrier(0) fences so the scheduler cannot sink the
// prefetch loads (R4 failure: loads sunk to uses, VGPR=56, latency-bound).
// Per-cell chain = ONE v_med3_f16: max(c,min(e,x)) == med3(c, max(e,c), x).
// ---------------------------------------------------------------------------

#define CELL(c_, pv_) { \
    _Float16 c = (c_); \
    _Float16 e = hmin_(pv_, diag); \
    _Float16 hm = hmax_(e, c); \
    _Float16 vv = med3h_(c, hm, left); \
    diag = pv_; pv_ = vv; left = vv; }

#define DP_STEP(PA, PB) { \
    int inc = __shfl_up(ro_bits, 1, 64); \
    _Float16 inch = __builtin_bit_cast(_Float16, (unsigned short)inc); \
    _Float16 left = (t == 0) ? lane0_left : inch; \
    _Float16 diag = (t == 0) ? HINF : diag_feed; \
    diag_feed = inch; \
    h2v u0 = __builtin_bit_cast(h2v, PA.x), u1 = __builtin_bit_cast(h2v, PA.y); \
    h2v u2 = __builtin_bit_cast(h2v, PA.z), u3 = __builtin_bit_cast(h2v, PA.w); \
    h2v u4 = __builtin_bit_cast(h2v, PB.x), u5 = __builtin_bit_cast(h2v, PB.y); \
    h2v u6 = __builtin_bit_cast(h2v, PB.z), u7 = __builtin_bit_cast(h2v, PB.w); \
    CELL(u0[0], v0)  CELL(u0[1], v1)  CELL(u1[0], v2)  CELL(u1[1], v3) \
    CELL(u2[0], v4)  CELL(u2[1], v5)  CELL(u3[0], v6)  CELL(u3[1], v7) \
    CELL(u4[0], v8)  CELL(u4[1], v9)  CELL(u5[0], v10) CELL(u5[1], v11) \
    CELL(u6[0], v12) CELL(u6[1], v13) CELL(u7[0], v14) CELL(u7[1], v15) \
    ro_bits = (int)(unsigned)__builtin_bit_cast(unsigned short, left); \
    lane0_left = HINF; }

#define RELOAD(n) { \
    __builtin_amdgcn_sched_barrier(0); \
    { const float4* p4 = (const float4*)q##n; \
      a##n = p4[0]; b##n = p4[1]; \
      q##n += (size_t)PD * T_LEN; } \
    __builtin_amdgcn_sched_barrier(0); }

#define INIT_SLOT(n) { \
    const float4* p4 = (const float4*)(Lp + (size_t)n * T_LEN); \
    a##n = p4[0]; b##n = p4[1]; \
    q##n = Lp + (size_t)(n + PD) * T_LEN; }

__global__ __launch_bounds__(64, 1) void dp_kernel_nb(const __half* __restrict__ cost,
                                                      float* __restrict__ out) {
    const int b = blockIdx.x;
    const int t = threadIdx.x;
    const _Float16 HINF = __builtin_bit_cast(_Float16, (unsigned short)0x7C00);
    const __half* Lp = cost + (size_t)b * SKEW_STRIDE + 16 * t;  // lane column window

    _Float16 v0 = HINF, v1 = HINF, v2 = HINF, v3 = HINF, v4 = HINF, v5 = HINF, v6 = HINF, v7 = HINF;
    _Float16 v8 = HINF, v9 = HINF, v10 = HINF, v11 = HINF, v12 = HINF, v13 = HINF, v14 = HINF, v15 = HINF;
    _Float16 diag_feed = HINF;
    _Float16 lane0_left = __builtin_bit_cast(_Float16, (unsigned short)0xFC00);  // -INF, first step only
    int ro_bits = 0x7C00;

    float4 a0, b0, a1, b1, a2, b2, a3, b3, a4, b4, a5, b5, a6, b6, a7, b7;
    const __half *q0, *q1, *q2, *q3, *q4, *q5, *q6, *q7;
    INIT_SLOT(0) INIT_SLOT(1) INIT_SLOT(2) INIT_SLOT(3)
    INIT_SLOT(4) INIT_SLOT(5) INIT_SLOT(6) INIT_SLOT(7)

    // 135 chunks x 8 steps = s 0..1079
#pragma unroll 1
    for (int chunk = 0; chunk < 135; ++chunk) {
        DP_STEP(a0, b0) RELOAD(0)
        DP_STEP(a1, b1) RELOAD(1)
        DP_STEP(a2, b2) RELOAD(2)
        DP_STEP(a3, b3) RELOAD(3)
        DP_STEP(a4, b4) RELOAD(4)
        DP_STEP(a5, b5) RELOAD(5)
        DP_STEP(a6, b6) RELOAD(6)
        DP_STEP(a7, b7) RELOAD(7)
    }
    // remainder: s = 1080..1086 (rows already resident in slots 0..6)
    DP_STEP(a0, b0)
    DP_STEP(a1, b1)
    DP_STEP(a2, b2)
    DP_STEP(a3, b3)
    DP_STEP(a4, b4)
    DP_STEP(a5, b5)
    DP_STEP(a6, b6)

    if (t == 63) atomicAdd(out, (float)v15 * (1.0f / (float)BATCH));
}

// ---------------------------------------------------------------------------
// Last-resort fused fallback (ws too small for skewed fp16 layout).
// ---------------------------------------------------------------------------
__global__ __launch_bounds__(64) void dp_fused_kernel(const float* __restrict__ pred,
                                                      const float* __restrict__ targ,
                                                      float* __restrict__ out) {
    const int b = blockIdx.x;
    const int t = threadIdx.x;
    const float INF = __builtin_inff();
    const float* P = pred + (size_t)b * T_LEN * D_DIM;
    const float* T = targ + (size_t)b * T_LEN * D_DIM + (size_t)(16 * t) * D_DIM;

    float prev[16];
#pragma unroll
    for (int j = 0; j < 16; j++) prev[j] = INF;
    float right_out = INF;
    float diag_feed = INF;

    for (int s = 0; s < T_LEN + 63; s++) {
        int r = s - t;
        float inc = __shfl_up(right_out, 1, 64);
        float left = inc, diag = diag_feed;
        diag_feed = inc;
        if (t == 0) { left = (r == 0) ? -INF : INF; diag = INF; }
        if (r >= 0 && r < T_LEN) {
            float4 pr[16];
            const float4* pp = (const float4*)(P + (size_t)r * D_DIM);
#pragma unroll
            for (int q = 0; q < 16; q++) pr[q] = pp[q];
#pragma unroll
            for (int j = 0; j < 16; j++) {
                const float4* tp = (const float4*)(T + (size_t)j * D_DIM);
                float acc = 0.0f;
#pragma unroll
                for (int q = 0; q < 16; q++) {
                    float4 tv = tp[q];
                    float dx = pr[q].x - tv.x; acc += dx * dx;
                    float dy = pr[q].y - tv.y; acc += dy * dy;
                    float dz = pr[q].z - tv.z; acc += dz * dz;
                    float dw = pr[q].w - tv.w; acc += dw * dw;
                }
                float c = sqrtf(fmaxf(acc, 1e-12f));
                float e = fminf(prev[j], diag);
                float hm = fmaxf(e, c);
                float vv = fmaxf(c, fminf(hm, left));
                diag = prev[j];
                prev[j] = vv;
                left = vv;
            }
            right_out = left;
        }
    }
    if (t == 63) atomicAdd(out, prev[15] * (1.0f / (float)BATCH));
}

extern "C" void kernel_launch(void* const* d_in, const int* in_sizes, int n_in,
                              void* d_out, int out_size, void* d_ws, size_t ws_size,
                              hipStream_t stream) {
    const float* pred = (const float*)d_in[0];
    const float* targ = (const float*)d_in[1];
    float* out = (float*)d_out;

    hipMemsetAsync(out, 0, sizeof(float) * out_size, stream);

    const size_t need = (size_t)BATCH * SKEW_STRIDE * sizeof(__half);  // ~74 MB

    if (ws_size >= need) {
        __half* ws = (__half*)d_ws;
        fill_stairs_kernel<<<dim3(63, 32), 128, 0, stream>>>(ws);
        cost_kernel<<<dim3(8, 8, BATCH), 256, 0, stream>>>(pred, targ, ws);
        dp_kernel_nb<<<BATCH, 64, 0, stream>>>(ws, out);
    } else {
        dp_fused_kernel<<<BATCH, 64, 0, stream>>>(pred, targ, out);
    }
}

// Round 6
// 366.757 us; speedup vs baseline: 1.0402x; 1.0402x over previous
//
#include <hip/hip_runtime.h>
#include <hip/hip_fp16.h>
#include <math.h>

#define T_LEN 1024
#define D_DIM 64
#define BATCH 32

// Skewed cost storage: element (r,c) lives at row (r + (c>>4)), col c.
// At DP step s, all 64 lanes read skewed row s contiguously (2 KB).
#define SKEW_ROWS 1104
#define SKEW_STRIDE ((size_t)SKEW_ROWS * T_LEN)

#define RING_SLOTS 32          // LDS ring rows (32 x 2 KB = 64 KB)
#define NBATCH 136             // 136 batches x 8 rows = rows 0..1087

typedef __attribute__((ext_vector_type(2))) _Float16 h2v;

static __device__ __forceinline__ _Float16 hmin_(_Float16 a, _Float16 b) {
#if __has_builtin(__builtin_fminf16)
    return __builtin_fminf16(a, b);
#else
    return (b < a) ? b : a;
#endif
}
static __device__ __forceinline__ _Float16 hmax_(_Float16 a, _Float16 b) {
#if __has_builtin(__builtin_fmaxf16)
    return __builtin_fmaxf16(a, b);
#else
    return (a < b) ? b : a;
#endif
}
static __device__ __forceinline__ _Float16 med3h_(_Float16 a, _Float16 b, _Float16 c) {
#if __has_builtin(__builtin_amdgcn_fmed3h)
    return __builtin_amdgcn_fmed3h(a, b, c);
#else
    return hmax_(a, hmin_(b, c));
#endif
}

// ---------------------------------------------------------------------------
// INF staircase: skewed row s (s<63), cols >= 16*(s+1) must be half(+INF).
// ---------------------------------------------------------------------------
__global__ __launch_bounds__(128) void fill_stairs_kernel(__half* __restrict__ ws) {
    int s = blockIdx.x;            // 0..62
    int b = blockIdx.y;            // 0..31
    int tid = threadIdx.x;         // 0..127
    int col0 = 16 * (s + 1);
    int n_u4 = (T_LEN - col0) >> 3;
    if (tid < n_u4) {
        __half* row = ws + (size_t)b * SKEW_STRIDE + (size_t)s * T_LEN + col0;
        ((uint4*)row)[tid] = make_uint4(0x7C007C00u, 0x7C007C00u, 0x7C007C00u, 0x7C007C00u);
    }
}

// ---------------------------------------------------------------------------
// Pairwise distances, 128x128 tile, 256 threads, 8x8 micro-tile, BK=32 x2.
// Output fp16 into the SKEWED layout: dest row = r + (col>>4).
// ---------------------------------------------------------------------------
__global__ __launch_bounds__(256) void cost_kernel(const float* __restrict__ pred,
                                                   const float* __restrict__ targ,
                                                   __half* __restrict__ skew_base) {
    const int b = blockIdx.z;
    const float* P = pred + (size_t)b * T_LEN * D_DIM;
    const float* T = targ + (size_t)b * T_LEN * D_DIM;
    __half* C = skew_base + (size_t)b * SKEW_STRIDE;
    const int row0 = blockIdx.y * 128;
    const int col0 = blockIdx.x * 128;

    __shared__ __align__(16) float ps[32][132];
    __shared__ __align__(16) float ts[32][132];
    __shared__ float p2[128], t2[128];

    const int tid = threadIdx.x;

    {
        int r = tid & 127;
        const float* src = (tid < 128) ? (P + (size_t)(row0 + r) * D_DIM)
                                       : (T + (size_t)(col0 + r) * D_DIM);
        float s = 0.0f;
#pragma unroll
        for (int q = 0; q < 16; q++) {
            float4 v = ((const float4*)src)[q];
            s += v.x * v.x + v.y * v.y + v.z * v.z + v.w * v.w;
        }
        if (tid < 128) p2[r] = s; else t2[r] = s;
    }

    const int lane = tid & 63, wv = tid >> 6;
    const int TX = (lane & 7) + 8 * (wv & 1);
    const int TY = (lane >> 3) + 8 * (wv >> 1);

    float acc[8][8];
#pragma unroll
    for (int i = 0; i < 8; i++)
#pragma unroll
        for (int j = 0; j < 8; j++) acc[i][j] = 0.0f;

#pragma unroll
    for (int chunk = 0; chunk < 2; ++chunk) {
        __syncthreads();
#pragma unroll
        for (int it = 0; it < 4; ++it) {
            int idx = tid + 256 * it;
            int row = idx >> 3;
            int kc = idx & 7;
            float4 v = *(const float4*)(P + (size_t)(row0 + row) * D_DIM + 32 * chunk + 4 * kc);
            ps[4 * kc + 0][row] = v.x; ps[4 * kc + 1][row] = v.y;
            ps[4 * kc + 2][row] = v.z; ps[4 * kc + 3][row] = v.w;
            float4 w = *(const float4*)(T + (size_t)(col0 + row) * D_DIM + 32 * chunk + 4 * kc);
            ts[4 * kc + 0][row] = w.x; ts[4 * kc + 1][row] = w.y;
            ts[4 * kc + 2][row] = w.z; ts[4 * kc + 3][row] = w.w;
        }
        __syncthreads();

#pragma unroll
        for (int kk = 0; kk < 32; ++kk) {
            float4 a0 = *(const float4*)&ps[kk][8 * TY];
            float4 a1 = *(const float4*)&ps[kk][8 * TY + 4];
            float4 b0 = *(const float4*)&ts[kk][8 * TX];
            float4 b1 = *(const float4*)&ts[kk][8 * TX + 4];
            float av[8] = {a0.x, a0.y, a0.z, a0.w, a1.x, a1.y, a1.z, a1.w};
            float bv[8] = {b0.x, b0.y, b0.z, b0.w, b1.x, b1.y, b1.z, b1.w};
#pragma unroll
            for (int i = 0; i < 8; i++)
#pragma unroll
                for (int j = 0; j < 8; j++) acc[i][j] += av[i] * bv[j];
        }
    }
    __syncthreads();

    const int skew = (col0 >> 4) + (TX >> 1);
#pragma unroll
    for (int i = 0; i < 8; i++) {
        float pa = p2[8 * TY + i];
        h2v o2[4];
#pragma unroll
        for (int j = 0; j < 4; j++) {
            float d0 = pa + t2[8 * TX + 2 * j]     - 2.0f * acc[i][2 * j];
            float d1 = pa + t2[8 * TX + 2 * j + 1] - 2.0f * acc[i][2 * j + 1];
            h2v h;
            h[0] = (_Float16)sqrtf(fmaxf(d0, 1e-12f));
            h[1] = (_Float16)sqrtf(fmaxf(d1, 1e-12f));
            o2[j] = h;
        }
        float4 st;
        st.x = __builtin_bit_cast(float, o2[0]);
        st.y = __builtin_bit_cast(float, o2[1]);
        st.z = __builtin_bit_cast(float, o2[2]);
        st.w = __builtin_bit_cast(float, o2[3]);
        __half* dst = C + (size_t)(row0 + 8 * TY + i + skew) * T_LEN + col0 + 8 * TX;
        *(float4*)dst = st;
    }
}

// ---------------------------------------------------------------------------
// Frechet DP, producer/consumer wave specialization.
// Wave 1 (producer): global->LDS DMA via global_load_lds (no VGPRs involved,
//   nothing for the RA/scheduler to sink -- the R1-R5 failure mode is gone).
// Wave 0 (consumer): fp16 med3 DP reading ONLY LDS (ds_read, ~120cy latency,
//   1-step ping-pong prefetch). Sync: acquire/release LDS flags per 8 rows.
// ---------------------------------------------------------------------------

__device__ __forceinline__ void gll16(const __half* g, __half* l) {
    __builtin_amdgcn_global_load_lds(
        (const __attribute__((address_space(1))) void*)g,
        (__attribute__((address_space(3))) void*)l,
        16, 0, 0);
}

#define CELL(c_, pv_) { \
    _Float16 c = (c_); \
    _Float16 e = hmin_(pv_, diag); \
    _Float16 hm = hmax_(e, c); \
    _Float16 vv = med3h_(c, hm, left); \
    diag = pv_; pv_ = vv; left = vv; }

#define DP_STEP(PA, PB) { \
    int inc = __shfl_up(ro_bits, 1, 64); \
    _Float16 inch = __builtin_bit_cast(_Float16, (unsigned short)inc); \
    _Float16 left = (t == 0) ? lane0_left : inch; \
    _Float16 diag = (t == 0) ? HINF : diag_feed; \
    diag_feed = inch; \
    h2v u0 = __builtin_bit_cast(h2v, PA.x), u1 = __builtin_bit_cast(h2v, PA.y); \
    h2v u2 = __builtin_bit_cast(h2v, PA.z), u3 = __builtin_bit_cast(h2v, PA.w); \
    h2v u4 = __builtin_bit_cast(h2v, PB.x), u5 = __builtin_bit_cast(h2v, PB.y); \
    h2v u6 = __builtin_bit_cast(h2v, PB.z), u7 = __builtin_bit_cast(h2v, PB.w); \
    CELL(u0[0], v0)  CELL(u0[1], v1)  CELL(u1[0], v2)  CELL(u1[1], v3) \
    CELL(u2[0], v4)  CELL(u2[1], v5)  CELL(u3[0], v6)  CELL(u3[1], v7) \
    CELL(u4[0], v8)  CELL(u4[1], v9)  CELL(u5[0], v10) CELL(u5[1], v11) \
    CELL(u6[0], v12) CELL(u6[1], v13) CELL(u7[0], v14) CELL(u7[1], v15) \
    ro_bits = (int)(unsigned)__builtin_bit_cast(unsigned short, left); \
    lane0_left = HINF; }

// one consumer step: consume nxt (row 8k+u), prefetch row 8k+u+1 if in batch
#define CSTEP(u, kk, PFGUARD) { \
    float4 cur0 = nxt0, cur1 = nxt1; \
    if ((u) < (PFGUARD)) { \
        const float4* np = (const float4*)(lb + (size_t)((8 * (kk) + (u) + 1) & 31) * 2048); \
        nxt0 = np[0]; nxt1 = np[1]; \
    } \
    DP_STEP(cur0, cur1) }

__global__ __launch_bounds__(128, 1) void dp_kernel_pc(const __half* __restrict__ cost,
                                                       float* __restrict__ out) {
    __shared__ __align__(16) __half ring[RING_SLOTS][T_LEN];   // 64 KB
    __shared__ int prod_done;
    __shared__ int cons_done;

    const int b = blockIdx.x;
    const int wave = threadIdx.x >> 6;
    const int t = threadIdx.x & 63;
    const __half* gbase = cost + (size_t)b * SKEW_STRIDE;

    if (threadIdx.x == 0) { prod_done = 0; cons_done = 0; }
    __syncthreads();

    if (wave == 1) {
        // ----- producer -----
        for (int k = 0; k < NBATCH; ++k) {
            while (__hip_atomic_load(&cons_done, __ATOMIC_ACQUIRE,
                                     __HIP_MEMORY_SCOPE_WORKGROUP) < k - 3) {
                __builtin_amdgcn_s_sleep(1);
            }
            const __half* gr = gbase + (size_t)(8 * k) * T_LEN;
#pragma unroll
            for (int u = 0; u < 8; ++u) {
                int slot = (8 * k + u) & 31;
                const __half* g = gr + (size_t)u * T_LEN;
                gll16(g + 8 * t, &ring[slot][0]);
                gll16(g + 512 + 8 * t, &ring[slot][512]);
            }
            __builtin_amdgcn_s_waitcnt(0);     // drain DMA before publishing
            if (t == 0) {
                __hip_atomic_store(&prod_done, k + 1, __ATOMIC_RELEASE,
                                   __HIP_MEMORY_SCOPE_WORKGROUP);
            }
        }
    } else {
        // ----- consumer -----
        const _Float16 HINF = __builtin_bit_cast(_Float16, (unsigned short)0x7C00);
        _Float16 v0 = HINF, v1 = HINF, v2 = HINF, v3 = HINF, v4 = HINF, v5 = HINF, v6 = HINF, v7 = HINF;
        _Float16 v8 = HINF, v9 = HINF, v10 = HINF, v11 = HINF, v12 = HINF, v13 = HINF, v14 = HINF, v15 = HINF;
        _Float16 diag_feed = HINF;
        _Float16 lane0_left = __builtin_bit_cast(_Float16, (unsigned short)0xFC00);  // -INF, first step only
        int ro_bits = 0x7C00;

        const char* lb = (const char*)&ring[0][0] + 32 * t;   // lane's 32B window
        float4 nxt0, nxt1;

        for (int k = 0; k < 135; ++k) {
            while (__hip_atomic_load(&prod_done, __ATOMIC_ACQUIRE,
                                     __HIP_MEMORY_SCOPE_WORKGROUP) < k + 1) {
                __builtin_amdgcn_s_sleep(1);
            }
            {   // first row of batch
                const float4* np = (const float4*)(lb + (size_t)((8 * k) & 31) * 2048);
                nxt0 = np[0]; nxt1 = np[1];
            }
            CSTEP(0, k, 7) CSTEP(1, k, 7) CSTEP(2, k, 7) CSTEP(3, k, 7)
            CSTEP(4, k, 7) CSTEP(5, k, 7) CSTEP(6, k, 7) CSTEP(7, k, 7)
            __hip_atomic_store(&cons_done, k + 1, __ATOMIC_RELEASE,
                               __HIP_MEMORY_SCOPE_WORKGROUP);
        }
        // tail batch 135: 7 steps (s = 1080..1086)
        while (__hip_atomic_load(&prod_done, __ATOMIC_ACQUIRE,
                                 __HIP_MEMORY_SCOPE_WORKGROUP) < 136) {
            __builtin_amdgcn_s_sleep(1);
        }
        {
            const float4* np = (const float4*)(lb + (size_t)((8 * 135) & 31) * 2048);
            nxt0 = np[0]; nxt1 = np[1];
        }
        CSTEP(0, 135, 6) CSTEP(1, 135, 6) CSTEP(2, 135, 6)
        CSTEP(3, 135, 6) CSTEP(4, 135, 6) CSTEP(5, 135, 6)
        CSTEP(6, 135, 6)

        if (t == 63) atomicAdd(out, (float)v15 * (1.0f / (float)BATCH));
    }
}

// ---------------------------------------------------------------------------
// Last-resort fused fallback (ws too small for skewed fp16 layout).
// ---------------------------------------------------------------------------
__global__ __launch_bounds__(64) void dp_fused_kernel(const float* __restrict__ pred,
                                                      const float* __restrict__ targ,
                                                      float* __restrict__ out) {
    const int b = blockIdx.x;
    const int t = threadIdx.x;
    const float INF = __builtin_inff();
    const float* P = pred + (size_t)b * T_LEN * D_DIM;
    const float* T = targ + (size_t)b * T_LEN * D_DIM + (size_t)(16 * t) * D_DIM;

    float prev[16];
#pragma unroll
    for (int j = 0; j < 16; j++) prev[j] = INF;
    float right_out = INF;
    float diag_feed = INF;

    for (int s = 0; s < T_LEN + 63; s++) {
        int r = s - t;
        float inc = __shfl_up(right_out, 1, 64);
        float left = inc, diag = diag_feed;
        diag_feed = inc;
        if (t == 0) { left = (r == 0) ? -INF : INF; diag = INF; }
        if (r >= 0 && r < T_LEN) {
            float4 pr[16];
            const float4* pp = (const float4*)(P + (size_t)r * D_DIM);
#pragma unroll
            for (int q = 0; q < 16; q++) pr[q] = pp[q];
#pragma unroll
            for (int j = 0; j < 16; j++) {
                const float4* tp = (const float4*)(T + (size_t)j * D_DIM);
                float acc = 0.0f;
#pragma unroll
                for (int q = 0; q < 16; q++) {
                    float4 tv = tp[q];
                    float dx = pr[q].x - tv.x; acc += dx * dx;
                    float dy = pr[q].y - tv.y; acc += dy * dy;
                    float dz = pr[q].z - tv.z; acc += dz * dz;
                    float dw = pr[q].w - tv.w; acc += dw * dw;
                }
                float c = sqrtf(fmaxf(acc, 1e-12f));
                float e = fminf(prev[j], diag);
                float hm = fmaxf(e, c);
                float vv = fmaxf(c, fminf(hm, left));
                diag = prev[j];
                prev[j] = vv;
                left = vv;
            }
            right_out = left;
        }
    }
    if (t == 63) atomicAdd(out, prev[15] * (1.0f / (float)BATCH));
}

extern "C" void kernel_launch(void* const* d_in, const int* in_sizes, int n_in,
                              void* d_out, int out_size, void* d_ws, size_t ws_size,
                              hipStream_t stream) {
    const float* pred = (const float*)d_in[0];
    const float* targ = (const float*)d_in[1];
    float* out = (float*)d_out;

    hipMemsetAsync(out, 0, sizeof(float) * out_size, stream);

    const size_t need = (size_t)BATCH * SKEW_STRIDE * sizeof(__half);  // ~72 MB

    if (ws_size >= need) {
        __half* ws = (__half*)d_ws;
        fill_stairs_kernel<<<dim3(63, 32), 128, 0, stream>>>(ws);
        cost_kernel<<<dim3(8, 8, BATCH), 256, 0, stream>>>(pred, targ, ws);
        dp_kernel_pc<<<BATCH, 128, 0, stream>>>(ws, out);
    } else {
        dp_fused_kernel<<<BATCH, 64, 0, stream>>>(pred, targ, out);
    }
}